// Round 1
// baseline (172.523 us; speedup 1.0000x reference)
//
#include <hip/hip_runtime.h>
#include <math.h>

// Problem shape (fixed): out (32,128,128,9,5) f32, target (32,128,128,3,6) f32
constexpr int kGX     = 128;
constexpr int kGY     = 128;
constexpr int kA      = 9;
constexpr int kNCells = 32 * kGX * kGY;              // 524288
constexpr int kN      = kNCells * kA;                // 4718592

constexpr int kGroups        = kN / 4;               // 1179648 (4 anchors/thread-group)
constexpr int kTiles         = kGroups / 256;        // 4608 tiles of 256 groups
constexpr int kTilesPerBlock = 2;
constexpr int kBlocks        = kTiles / kTilesPerBlock;  // 2304
static_assert(kBlocks * kTilesPerBlock * 256 * 4 == kN, "exact cover");

__device__ inline float frcp(float x) { return __builtin_amdgcn_rcpf(x); }

// Branchless full-range atan, A&S 4.4.49 poly on [0,1] (|eps| <= 1e-5).
__device__ inline float fast_atan(float r) {
    const float x = fabsf(r);
    const bool inv = x > 1.f;
    const float t = inv ? frcp(x) : x;
    const float t2 = t * t;
    float p = fmaf(t2, 0.0208351f, -0.0851330f);
    p = fmaf(t2, p, 0.1801410f);
    p = fmaf(t2, p, -0.3302995f);
    p = fmaf(t2, p, 0.9998660f);
    p = t * p;
    float res = inv ? (1.5707963f - p) : p;
    return r < 0.f ? -res : res;
}

struct Rec {   // per-cell precomputed invariants
    float ax1, ax2, ay1, ay2, acx, acy, area, atg, zx, zy, posf;
};

__device__ inline Rec make_rec(const float* __restrict__ tgt, int cell) {
    const float2* t2p = (const float2*)(tgt + (size_t)cell * 18);
    const float2 a01 = t2p[0];               // acx, acy
    const float2 a23 = t2p[1];               // aw, ah
    const float conf = ((const float*)t2p)[5];
    Rec r;
    r.acx = a01.x; r.acy = a01.y;
    r.ax1 = a01.x - 0.5f * a23.x; r.ax2 = a01.x + 0.5f * a23.x;
    r.ay1 = a01.y - 0.5f * a23.y; r.ay2 = a01.y + 0.5f * a23.y;
    r.area = a23.x * a23.y;
    r.atg  = fast_atan(a23.x * frcp(a23.y));
    const int gy = cell & (kGY - 1);
    const int gx = (cell >> 7) & (kGX - 1);
    r.zx = (float)gx * (1.f / kGX) + 0.5f / kGX;
    r.zy = (float)gy * (1.f / kGY) + 0.5f / kGY;
    r.posf = (conf > 0.8f) ? 1.f : 0.f;
    return r;
}

// acc: mode==1 -> per-block partials acc[b*5+i]; mode==0 -> 5 global doubles (atomics)
__global__ __launch_bounds__(256)
void loss_main(const float* __restrict__ outp, const float* __restrict__ tgt,
               double* __restrict__ acc, int mode) {
    // One tile of `out`: 256 groups x 20 floats = 5120 floats = 20 KB.
    __shared__ float4 sbuf[1280];

    const int tid = threadIdx.x;
    float t_jsq = 0.f, t_all = 0.f, t_jbb = 0.f, t_huh = 0.f, t_zsd = 0.f;

    for (int tt = 0; tt < kTilesPerBlock; ++tt) {
        const int tile = blockIdx.x * kTilesPerBlock + tt;
        const int gid  = tile * 256 + tid;
        const int a0   = gid * 4;

        // ---- per-thread target records (independent global loads, issue early) ----
        const int cell0 = (int)(__umulhi((unsigned)a0, 0x38E38E39u) >> 1);  // a0/9
        const int r0    = a0 - cell0 * 9;
        const int cell1 = min(cell0 + 1, kNCells - 1);   // clamp (never selected if OOB)
        const Rec RA = make_rec(tgt, cell0);
        const Rec RB = make_rec(tgt, cell1);

        // ---- coalesced stage of the out-tile: lane-contiguous float4 loads ----
        if (tt) __syncthreads();                 // protect sbuf reuse across tiles
        const float4* src = (const float4*)outp + (size_t)tile * 1280;
        #pragma unroll
        for (int k = 0; k < 5; ++k) sbuf[k * 256 + tid] = src[k * 256 + tid];
        __syncthreads();

        // ---- per-thread 80B read back from LDS (stride 20 dwords: bank-uniform) ----
        const float* so = (const float*)sbuf + tid * 20;
        const float4 q0 = *(const float4*)(so +  0);
        const float4 q1 = *(const float4*)(so +  4);
        const float4 q2 = *(const float4*)(so +  8);
        const float4 q3 = *(const float4*)(so + 12);
        const float4 q4 = *(const float4*)(so + 16);

        const float o[20] = {q0.x, q0.y, q0.z, q0.w, q1.x, q1.y, q1.z, q1.w,
                             q2.x, q2.y, q2.z, q2.w, q3.x, q3.y, q3.z, q3.w,
                             q4.x, q4.y, q4.z, q4.w};

        #pragma unroll
        for (int j = 0; j < 4; ++j) {
            const bool cross = (r0 + j) >= 9;
            const float ax1 = cross ? RB.ax1 : RA.ax1, ax2 = cross ? RB.ax2 : RA.ax2;
            const float ay1 = cross ? RB.ay1 : RA.ay1, ay2 = cross ? RB.ay2 : RA.ay2;
            const float acx = cross ? RB.acx : RA.acx, acy = cross ? RB.acy : RA.acy;
            const float area_a = cross ? RB.area : RA.area;
            const float atan_a = cross ? RB.atg : RA.atg;
            const float zx = cross ? RB.zx : RA.zx, zy = cross ? RB.zy : RA.zy;
            const float posf = cross ? RB.posf : RA.posf;
            const bool pos = posf > 0.5f;

            const float o0 = o[j * 5 + 0], o1 = o[j * 5 + 1], o2 = o[j * 5 + 2];
            const float o3 = o[j * 5 + 3], obj = o[j * 5 + 4];

            const float bcx = o0 - 0.5f + zx;
            const float bcy = o1 - 0.5f + zy;
            const float bw  = o2 - 0.5f + (1.f / kGX);
            const float bh  = o3 - 0.5f + (1.f / kGY);
            const float bx1 = bcx - 0.5f * bw, bx2 = bcx + 0.5f * bw;
            const float by1 = bcy - 0.5f * bh, by2 = bcy + 0.5f * bh;

            const float iw = fminf(ax2, bx2) - fmaxf(ax1, bx1);
            const float ih = fminf(ay2, by2) - fmaxf(ay1, by1);
            const float cross_a = (iw > 0.f && ih > 0.f) ? iw * ih : 0.f;
            const float uni = area_a + bw * bh - cross_a;
            const float iou = cross_a * frcp(uni + 1e-6f);

            const float dx = bcx - acx, dy = bcy - acy;
            const float d2 = dx * dx + dy * dy;
            const float cw  = fmaxf(ax2, bx2) - fminf(ax1, bx1);
            const float chh = fmaxf(ay2, by2) - fminf(ay1, by1);
            const float c2 = cw * cw + chh * chh;
            const float diou = iou - d2 * frcp(c2);

            const float dat = atan_a - fast_atan(bw * frcp(bh));
            const float v = 0.4052847345693511f * dat * dat;   // 4/pi^2
            const float alpha = v * frcp(1.f - iou + v);
            const float los = 1.f - (diou - alpha * v);
            const float om = 1.f - obj;

            t_jsq += posf;
            t_all += pos ? (los + om) : 0.f;
            t_jbb += pos ? iou : 0.f;
            t_huh += pos ? om : 0.f;
            t_zsd += pos ? om * om : obj * obj;
        }
    }

    // ---- wave-64 butterfly reduce (float), cross-wave via LDS, block partial ----
    const int lane = threadIdx.x & 63;
    const int wv   = threadIdx.x >> 6;
    float vals[5] = {t_jsq, t_all, t_jbb, t_huh, t_zsd};
    #pragma unroll
    for (int i = 0; i < 5; ++i) {
        float x = vals[i];
        #pragma unroll
        for (int off = 32; off > 0; off >>= 1) x += __shfl_down(x, off, 64);
        vals[i] = x;
    }
    __shared__ float smem[4][5];
    __syncthreads();                 // sbuf reads done before smem aliasing concerns
    if (lane == 0) {
        #pragma unroll
        for (int i = 0; i < 5; ++i) smem[wv][i] = vals[i];
    }
    __syncthreads();
    if (threadIdx.x < 5) {
        const double sv = (double)smem[0][threadIdx.x] + (double)smem[1][threadIdx.x] +
                          (double)smem[2][threadIdx.x] + (double)smem[3][threadIdx.x];
        if (mode) acc[(size_t)blockIdx.x * 5 + threadIdx.x] = sv;
        else atomicAdd(&acc[threadIdx.x], sv);
    }
}

__global__ __launch_bounds__(256)
void loss_final(const double* __restrict__ acc, float* __restrict__ res, int n_part) {
    if (n_part > 0) {
        double v[5] = {0, 0, 0, 0, 0};
        for (int j = threadIdx.x; j < n_part; j += 256) {
            #pragma unroll
            for (int i = 0; i < 5; ++i) v[i] += acc[(size_t)j * 5 + i];
        }
        #pragma unroll
        for (int i = 0; i < 5; ++i) {
            double x = v[i];
            #pragma unroll
            for (int off = 32; off > 0; off >>= 1) x += __shfl_down(x, off, 64);
            v[i] = x;
        }
        __shared__ double sm[4][5];
        const int lane = threadIdx.x & 63, wv = threadIdx.x >> 6;
        if (lane == 0) {
            #pragma unroll
            for (int i = 0; i < 5; ++i) sm[wv][i] = v[i];
        }
        __syncthreads();
        if (threadIdx.x == 0) {
            #pragma unroll
            for (int i = 0; i < 5; ++i) v[i] = sm[0][i] + sm[1][i] + sm[2][i] + sm[3][i];
            const double jsq = v[0], total = (double)kN;
            res[0] = (float)(v[1] / jsq + v[4] / total);
            res[1] = (float)(v[2] / jsq);
            res[2] = (float)(v[3] / jsq);
        }
    } else if (threadIdx.x == 0) {
        const double jsq = acc[0], total = (double)kN;
        res[0] = (float)(acc[1] / jsq + acc[4] / total);
        res[1] = (float)(acc[2] / jsq);
        res[2] = (float)(acc[3] / jsq);
    }
}

extern "C" void kernel_launch(void* const* d_in, const int* in_sizes, int n_in,
                              void* d_out, int out_size, void* d_ws, size_t ws_size,
                              hipStream_t stream) {
    const float* outp = (const float*)d_in[0];
    const float* tgt  = (const float*)d_in[1];
    float* res = (float*)d_out;
    double* acc = (double*)d_ws;

    const bool partials = ws_size >= (size_t)kBlocks * 5 * sizeof(double);  // 92 KB
    if (!partials) hipMemsetAsync(acc, 0, 5 * sizeof(double), stream);
    loss_main<<<kBlocks, 256, 0, stream>>>(outp, tgt, acc, partials ? 1 : 0);
    loss_final<<<1, 256, 0, stream>>>(acc, res, partials ? kBlocks : 0);
}